// Round 8
// baseline (435.412 us; speedup 1.0000x reference)
//
#include <hip/hip_runtime.h>
#include <hip/hip_bf16.h>

// ---------------------------------------------------------------------------
// GCN forward: hierarchical atomic-free CSR build (16-padded per-node lists)
// -> MFMA gemm1 -> 2x fused (gather-agg -> MFMA gemm) -> agg3 (bf16 out) ->
// fused pool+FC head.
// hs = dis[n]*h[n] in bf16 (+zero dummy row N), ping-pong hsb/hs2.
// k_aggemm: block = 64 nodes; 4 waves gather 16 nodes each (padded colidx,
// branchless 32-edge blocks, butterfly reduce), relu'd v -> LDS bf16 A-tile,
// then v_mfma_f32_16x16x32_bf16 x W_next, dis-scaled bf16 out.
// NOTE (R5 lesson): NO float LDS atomics — CAS loop, ~20x cost.
// ---------------------------------------------------------------------------

#define NBLK 256        // partition blocks
#define MAXNB 1024      // max buckets supported (N <= 131072)
#define FCAP 4608       // LDS edge-staging capacity in k_fine
#define BPAD 2048       // per-bucket colidx padding slack

typedef __attribute__((ext_vector_type(8))) short short8;    // 8 bf16 (4 VGPR)
typedef __attribute__((ext_vector_type(4))) float floatx4;   // MFMA acc

__device__ __forceinline__ float bf2f(unsigned short v) {
    return __uint_as_float(((unsigned int)v) << 16);
}
__device__ __forceinline__ unsigned short f2bf(float x) {
    __hip_bfloat16 b = __float2bfloat16(x);  // round-to-nearest
    return *(unsigned short*)&b;
}
__device__ __forceinline__ float4 bf4(ushort4 v) {
    return make_float4(bf2f(v.x), bf2f(v.y), bf2f(v.z), bf2f(v.w));
}

// P1: per-block bucket histogram (int4-vectorized edge reads).
__global__ __launch_bounds__(256) void k_hist(const int* __restrict__ dst,
                                              int* __restrict__ blockhist,
                                              int E, int chunk, int nb) {
    __shared__ int h[MAXNB];
    int b = blockIdx.x, t = threadIdx.x;
    for (int j = t; j < nb; j += 256) h[j] = 0;
    __syncthreads();
    int lo = b * chunk, hi = min(lo + chunk, E);
    int m = hi - lo;
    int nv = m >> 2;
    const int4* d4 = (const int4*)(dst + lo);
    for (int i = t; i < nv; i += 256) {
        int4 v = d4[i];
        atomicAdd(&h[v.x >> 7], 1);
        atomicAdd(&h[v.y >> 7], 1);
        atomicAdd(&h[v.z >> 7], 1);
        atomicAdd(&h[v.w >> 7], 1);
    }
    for (int i = lo + (nv << 2) + t; i < hi; i += 256) atomicAdd(&h[dst[i] >> 7], 1);
    __syncthreads();
    for (int j = t; j < nb; j += 256) blockhist[j * NBLK + b] = h[j];
}

// P2a: per-bucket exclusive scan over blocks (in place); btotal[j] = total.
__global__ __launch_bounds__(256) void k_bscan(int* __restrict__ blockhist,
                                               int* __restrict__ btotal) {
    __shared__ int sm[256];
    int j = blockIdx.x, t = threadIdx.x;
    int v = blockhist[j * NBLK + t];
    sm[t] = v;
    __syncthreads();
    for (int d = 1; d < 256; d <<= 1) {
        int u = (t >= d) ? sm[t - d] : 0;
        __syncthreads();
        sm[t] += u;
        __syncthreads();
    }
    blockhist[j * NBLK + t] = sm[t] - v;
    if (t == 255) btotal[j] = sm[255];
}

// P2b: single-block exclusive scan of bucket totals -> starts[0..nb].
// Also zeroes the dummy hs rows (index N) of both ping-pong buffers.
__global__ __launch_bounds__(256) void k_sscan(const int* __restrict__ btotal,
                                               int* __restrict__ starts, int nb,
                                               unsigned short* __restrict__ z1,
                                               unsigned short* __restrict__ z2,
                                               int N) {
    __shared__ int sm[256];
    int t = threadIdx.x;
    if (t < 64) {
        z1[(size_t)N * 64 + t] = 0;
        z2[(size_t)N * 64 + t] = 0;
    }
    int base = t * 4;
    int v0 = (base + 0 < nb) ? btotal[base + 0] : 0;
    int v1 = (base + 1 < nb) ? btotal[base + 1] : 0;
    int v2 = (base + 2 < nb) ? btotal[base + 2] : 0;
    int v3 = (base + 3 < nb) ? btotal[base + 3] : 0;
    int tsum = v0 + v1 + v2 + v3;
    sm[t] = tsum;
    __syncthreads();
    for (int d = 1; d < 256; d <<= 1) {
        int u = (t >= d) ? sm[t - d] : 0;
        __syncthreads();
        sm[t] += u;
        __syncthreads();
    }
    int excl = sm[t] - tsum;
    if (base + 0 < nb) starts[base + 0] = excl;
    if (base + 1 < nb) starts[base + 1] = excl + v0;
    if (base + 2 < nb) starts[base + 2] = excl + v0 + v1;
    if (base + 3 < nb) starts[base + 3] = excl + v0 + v1 + v2;
    if (t == 255) starts[nb] = sm[255];
}

// P3: partition edges into bucket regions. epart = src | (dst&127)<<17.
__global__ __launch_bounds__(256) void k_part(const int* __restrict__ src,
                                              const int* __restrict__ dst,
                                              const int* __restrict__ blockhist,
                                              const int* __restrict__ starts,
                                              unsigned int* __restrict__ epart,
                                              int E, int chunk, int nb) {
    __shared__ int cur[MAXNB];
    int b = blockIdx.x, t = threadIdx.x;
    for (int j = t; j < nb; j += 256) cur[j] = starts[j] + blockhist[j * NBLK + b];
    __syncthreads();
    int lo = b * chunk, hi = min(lo + chunk, E);
    int m = hi - lo;
    int nv = m >> 2;
    const int4* d4 = (const int4*)(dst + lo);
    const int4* s4 = (const int4*)(src + lo);
    for (int i = t; i < nv; i += 256) {
        int4 d = d4[i];
        int4 s = s4[i];
        int p;
        p = atomicAdd(&cur[d.x >> 7], 1); epart[p] = (unsigned int)s.x | ((unsigned int)(d.x & 127) << 17);
        p = atomicAdd(&cur[d.y >> 7], 1); epart[p] = (unsigned int)s.y | ((unsigned int)(d.y & 127) << 17);
        p = atomicAdd(&cur[d.z >> 7], 1); epart[p] = (unsigned int)s.z | ((unsigned int)(d.z & 127) << 17);
        p = atomicAdd(&cur[d.w >> 7], 1); epart[p] = (unsigned int)s.w | ((unsigned int)(d.w & 127) << 17);
    }
    for (int i = lo + (nv << 2) + t; i < hi; i += 256) {
        int d = dst[i];
        int pos = atomicAdd(&cur[d >> 7], 1);
        epart[pos] = (unsigned int)src[i] | ((unsigned int)(d & 127) << 17);
    }
}

// P4: per-bucket fine sort with padded per-node lists (pad src = N).
__global__ __launch_bounds__(256) void k_fine(const unsigned int* __restrict__ epart,
                                              const int* __restrict__ starts,
                                              int* __restrict__ deg,
                                              int* __restrict__ rowptr,
                                              float* __restrict__ dis,
                                              int* __restrict__ colidx, int N) {
    __shared__ unsigned int eb[FCAP];
    __shared__ int cnt[128], sc[128], cur[128];
    int j = blockIdx.x, t = threadIdx.x;
    int n0 = j << 7;
    int nn = min(128, N - n0);
    int s = starts[j], e = starts[j + 1];
    int m = e - s;
    int pbase = s + j * BPAD;
    if (t < 128) cnt[t] = 0;
    __syncthreads();
    for (int i = t; i < m; i += 256) {
        unsigned int p = epart[s + i];
        if (i < FCAP) eb[i] = p;
        atomicAdd(&cnt[p >> 17], 1);
    }
    __syncthreads();
    int pcv = 0;
    if (t < 128) { pcv = (cnt[t] + 15) & ~15; sc[t] = pcv; }
    __syncthreads();
    for (int d = 1; d < 128; d <<= 1) {
        int u = (t < 128 && t >= d) ? sc[t - d] : 0;
        __syncthreads();
        if (t < 128) sc[t] += u;
        __syncthreads();
    }
    if (t < nn) {
        int c = cnt[t];
        int rp = pbase + sc[t] - pcv;
        deg[n0 + t] = c;
        rowptr[n0 + t] = rp;
        dis[n0 + t] = rsqrtf((float)c + 1.0f);
        cur[t] = rp;
    }
    __syncthreads();
    for (int i = t; i < m; i += 256) {
        unsigned int p = (i < FCAP) ? eb[i] : epart[s + i];
        int pos = atomicAdd(&cur[p >> 17], 1);
        colidx[pos] = (int)(p & 0x1FFFF);
    }
    __syncthreads();
    if (t < nn) {
        int endp = rowptr[n0 + t] + ((cnt[t] + 15) & ~15);
        for (int q = cur[t]; q < endp; ++q) colidx[q] = N;  // dummy row
    }
}

// MFMA GEMM: C[64x64] per block = A[64xK] * W[Kx64]; bf16 in, fp32 acc.
// Epilogue scales by dis[row], stores bf16 hs. (layer 1: fp32 x input)
template <int K>
__global__ __launch_bounds__(256) void k_gemm_mfma(const float* __restrict__ A,
                                                   const float* __restrict__ W,
                                                   const float* __restrict__ dis,
                                                   unsigned short* __restrict__ hs,
                                                   int N) {
    constexpr int AS = K + 8;
    __shared__ unsigned short As[64 * AS];
    __shared__ unsigned short Bt[64 * AS];
    const int tid = threadIdx.x;
    const int r0 = blockIdx.x * 64;

    for (int idx = tid; idx < K * 64; idx += 256) {
        int k = idx >> 6, n = idx & 63;
        Bt[n * AS + k] = f2bf(W[idx]);
    }
    for (int idx = tid; idx < 64 * (K / 4); idx += 256) {
        int row = idx / (K / 4), kq = idx % (K / 4);
        int gr = r0 + row;
        float4 a = (gr < N) ? ((const float4*)(A + (size_t)gr * K))[kq]
                            : make_float4(0.f, 0.f, 0.f, 0.f);
        ushort4 v;
        v.x = f2bf(a.x); v.y = f2bf(a.y); v.z = f2bf(a.z); v.w = f2bf(a.w);
        *(ushort4*)&As[row * AS + kq * 4] = v;
    }
    __syncthreads();

    const int w = tid >> 6, lane = tid & 63;
    const int m = lane & 15, quad = lane >> 4;
    floatx4 acc0 = {0.f, 0.f, 0.f, 0.f};
    floatx4 acc1 = {0.f, 0.f, 0.f, 0.f};
    floatx4 acc2 = {0.f, 0.f, 0.f, 0.f};
    floatx4 acc3 = {0.f, 0.f, 0.f, 0.f};
#pragma unroll
    for (int s = 0; s < K / 32; ++s) {
        int ko = s * 32 + quad * 8;
        short8 a  = *(const short8*)&As[(w * 16 + m) * AS + ko];
        short8 b0 = *(const short8*)&Bt[(0 * 16 + m) * AS + ko];
        short8 b1 = *(const short8*)&Bt[(1 * 16 + m) * AS + ko];
        short8 b2 = *(const short8*)&Bt[(2 * 16 + m) * AS + ko];
        short8 b3 = *(const short8*)&Bt[(3 * 16 + m) * AS + ko];
        acc0 = __builtin_amdgcn_mfma_f32_16x16x32_bf16(a, b0, acc0, 0, 0, 0);
        acc1 = __builtin_amdgcn_mfma_f32_16x16x32_bf16(a, b1, acc1, 0, 0, 0);
        acc2 = __builtin_amdgcn_mfma_f32_16x16x32_bf16(a, b2, acc2, 0, 0, 0);
        acc3 = __builtin_amdgcn_mfma_f32_16x16x32_bf16(a, b3, acc3, 0, 0, 0);
    }
#pragma unroll
    for (int r = 0; r < 4; ++r) {
        int gr = r0 + w * 16 + quad * 4 + r;
        if (gr < N) {
            float dn = dis[gr];
            size_t base = (size_t)gr * 64 + m;
            hs[base + 0]  = f2bf(acc0[r] * dn);
            hs[base + 16] = f2bf(acc1[r] * dn);
            hs[base + 32] = f2bf(acc2[r] * dn);
            hs[base + 48] = f2bf(acc3[r] * dn);
        }
    }
}

// Fused gather-aggregate + MFMA GEMM (layer boundary). Block = 64 nodes.
// Phase A: wave w gathers nodes w*16..w*16+15 (lane = eslot x chquad,
// padded x16 lists, butterfly reduce), relu'd v -> bf16 LDS A-tile.
// Phase B: A-tile x W (16x16x32 MFMA), dis-scaled bf16 hs_out.
__global__ __launch_bounds__(256) void k_aggemm(const unsigned short* __restrict__ hs_in,
                                                const int* __restrict__ rowptr,
                                                const int* __restrict__ deg,
                                                const int* __restrict__ colidx,
                                                const float* __restrict__ dis,
                                                const float* __restrict__ bias,
                                                const float* __restrict__ W,
                                                unsigned short* __restrict__ hs_out,
                                                int N) {
    constexpr int AS = 72;
    __shared__ unsigned short As[64 * AS];
    __shared__ unsigned short Bt[64 * AS];
    const int tid = threadIdx.x;
    const int r0 = blockIdx.x * 64;
    const int w = tid >> 6, lane = tid & 63;

    // stage W [64][64] fp32 -> Bt[n][k] bf16 (transposed)
    for (int idx = tid; idx < 64 * 64; idx += 256) {
        int k = idx >> 6, n = idx & 63;
        Bt[n * AS + k] = f2bf(W[idx]);
    }

    // Phase A: gather 16 nodes per wave
    int eslot = lane >> 4;
    int cq = lane & 15;
    float4 bb = *(const float4*)&bias[cq * 4];
    for (int i = 0; i < 16; ++i) {
        int node = r0 + w * 16 + i;
        float4 acc = make_float4(0.f, 0.f, 0.f, 0.f);
        if (node < N) {
            int start = rowptr[node];
            int cnt = deg[node];
            int pcnt = (cnt + 15) & ~15;
            const int* ci = colidx + start + eslot;
            int k = 0;
            if (pcnt & 16) {
                int s0 = ci[0], s1 = ci[4], s2 = ci[8], s3 = ci[12];
                ushort4 a0 = *(const ushort4*)&hs_in[(size_t)s0 * 64 + cq * 4];
                ushort4 a1 = *(const ushort4*)&hs_in[(size_t)s1 * 64 + cq * 4];
                ushort4 a2 = *(const ushort4*)&hs_in[(size_t)s2 * 64 + cq * 4];
                ushort4 a3 = *(const ushort4*)&hs_in[(size_t)s3 * 64 + cq * 4];
                float4 f0 = bf4(a0), f1 = bf4(a1), f2 = bf4(a2), f3 = bf4(a3);
                acc.x += f0.x + f1.x + f2.x + f3.x;
                acc.y += f0.y + f1.y + f2.y + f3.y;
                acc.z += f0.z + f1.z + f2.z + f3.z;
                acc.w += f0.w + f1.w + f2.w + f3.w;
                k = 16;
            }
            for (; k < pcnt; k += 32) {
                int s0 = ci[k + 0],  s1 = ci[k + 4],  s2 = ci[k + 8],  s3 = ci[k + 12];
                int s4 = ci[k + 16], s5 = ci[k + 20], s6 = ci[k + 24], s7 = ci[k + 28];
                ushort4 a0 = *(const ushort4*)&hs_in[(size_t)s0 * 64 + cq * 4];
                ushort4 a1 = *(const ushort4*)&hs_in[(size_t)s1 * 64 + cq * 4];
                ushort4 a2 = *(const ushort4*)&hs_in[(size_t)s2 * 64 + cq * 4];
                ushort4 a3 = *(const ushort4*)&hs_in[(size_t)s3 * 64 + cq * 4];
                ushort4 a4 = *(const ushort4*)&hs_in[(size_t)s4 * 64 + cq * 4];
                ushort4 a5 = *(const ushort4*)&hs_in[(size_t)s5 * 64 + cq * 4];
                ushort4 a6 = *(const ushort4*)&hs_in[(size_t)s6 * 64 + cq * 4];
                ushort4 a7 = *(const ushort4*)&hs_in[(size_t)s7 * 64 + cq * 4];
                float4 f0 = bf4(a0), f1 = bf4(a1), f2 = bf4(a2), f3 = bf4(a3);
                float4 f4 = bf4(a4), f5 = bf4(a5), f6 = bf4(a6), f7 = bf4(a7);
                acc.x += (f0.x + f1.x) + (f2.x + f3.x) + (f4.x + f5.x) + (f6.x + f7.x);
                acc.y += (f0.y + f1.y) + (f2.y + f3.y) + (f4.y + f5.y) + (f6.y + f7.y);
                acc.z += (f0.z + f1.z) + (f2.z + f3.z) + (f4.z + f5.z) + (f6.z + f7.z);
                acc.w += (f0.w + f1.w) + (f2.w + f3.w) + (f4.w + f5.w) + (f6.w + f7.w);
            }
        }
        acc.x += __shfl_xor(acc.x, 16, 64);
        acc.y += __shfl_xor(acc.y, 16, 64);
        acc.z += __shfl_xor(acc.z, 16, 64);
        acc.w += __shfl_xor(acc.w, 16, 64);
        acc.x += __shfl_xor(acc.x, 32, 64);
        acc.y += __shfl_xor(acc.y, 32, 64);
        acc.z += __shfl_xor(acc.z, 32, 64);
        acc.w += __shfl_xor(acc.w, 32, 64);
        if (eslot == 0) {
            ushort4 o = {0, 0, 0, 0};
            if (node < N) {
                ushort4 sv = *(const ushort4*)&hs_in[(size_t)node * 64 + cq * 4];
                float4 sf = bf4(sv);
                float dn = dis[node];
                float vx = fmaxf(dn * (acc.x + sf.x) + bb.x, 0.f);
                float vy = fmaxf(dn * (acc.y + sf.y) + bb.y, 0.f);
                float vz = fmaxf(dn * (acc.z + sf.z) + bb.z, 0.f);
                float vw = fmaxf(dn * (acc.w + sf.w) + bb.w, 0.f);
                o.x = f2bf(vx); o.y = f2bf(vy); o.z = f2bf(vz); o.w = f2bf(vw);
            }
            *(ushort4*)&As[(w * 16 + i) * AS + cq * 4] = o;
        }
    }
    __syncthreads();

    // Phase B: MFMA, A-tile from LDS
    const int m = lane & 15, quad = lane >> 4;
    floatx4 acc0 = {0.f, 0.f, 0.f, 0.f};
    floatx4 acc1 = {0.f, 0.f, 0.f, 0.f};
    floatx4 acc2 = {0.f, 0.f, 0.f, 0.f};
    floatx4 acc3 = {0.f, 0.f, 0.f, 0.f};
#pragma unroll
    for (int s = 0; s < 2; ++s) {
        int ko = s * 32 + quad * 8;
        short8 a  = *(const short8*)&As[(w * 16 + m) * AS + ko];
        short8 b0 = *(const short8*)&Bt[(0 * 16 + m) * AS + ko];
        short8 b1 = *(const short8*)&Bt[(1 * 16 + m) * AS + ko];
        short8 b2 = *(const short8*)&Bt[(2 * 16 + m) * AS + ko];
        short8 b3 = *(const short8*)&Bt[(3 * 16 + m) * AS + ko];
        acc0 = __builtin_amdgcn_mfma_f32_16x16x32_bf16(a, b0, acc0, 0, 0, 0);
        acc1 = __builtin_amdgcn_mfma_f32_16x16x32_bf16(a, b1, acc1, 0, 0, 0);
        acc2 = __builtin_amdgcn_mfma_f32_16x16x32_bf16(a, b2, acc2, 0, 0, 0);
        acc3 = __builtin_amdgcn_mfma_f32_16x16x32_bf16(a, b3, acc3, 0, 0, 0);
    }
#pragma unroll
    for (int r = 0; r < 4; ++r) {
        int gr = r0 + w * 16 + quad * 4 + r;
        if (gr < N) {
            float dn = dis[gr];
            size_t base = (size_t)gr * 64 + m;
            hs_out[base + 0]  = f2bf(acc0[r] * dn);
            hs_out[base + 16] = f2bf(acc1[r] * dn);
            hs_out[base + 32] = f2bf(acc2[r] * dn);
            hs_out[base + 48] = f2bf(acc3[r] * dn);
        }
    }
}

// Final aggregate (layer 3): bf16 out, no relu.
__global__ __launch_bounds__(256) void k_agg3(const unsigned short* __restrict__ hs,
                                              const int* __restrict__ rowptr,
                                              const int* __restrict__ deg,
                                              const int* __restrict__ colidx,
                                              const float* __restrict__ dis,
                                              const float* __restrict__ bias,
                                              unsigned short* __restrict__ outp,
                                              int N) {
    int node = blockIdx.x * 4 + (threadIdx.x >> 6);
    if (node >= N) return;
    int lane = threadIdx.x & 63;
    int eslot = lane >> 4;
    int cq = lane & 15;

    int start = rowptr[node];
    int cnt = deg[node];
    int pcnt = (cnt + 15) & ~15;
    const int* ci = colidx + start + eslot;
    float4 acc = make_float4(0.f, 0.f, 0.f, 0.f);

    int i = 0;
    if (pcnt & 16) {
        int s0 = ci[0], s1 = ci[4], s2 = ci[8], s3 = ci[12];
        ushort4 a0 = *(const ushort4*)&hs[(size_t)s0 * 64 + cq * 4];
        ushort4 a1 = *(const ushort4*)&hs[(size_t)s1 * 64 + cq * 4];
        ushort4 a2 = *(const ushort4*)&hs[(size_t)s2 * 64 + cq * 4];
        ushort4 a3 = *(const ushort4*)&hs[(size_t)s3 * 64 + cq * 4];
        float4 f0 = bf4(a0), f1 = bf4(a1), f2 = bf4(a2), f3 = bf4(a3);
        acc.x += f0.x + f1.x + f2.x + f3.x;
        acc.y += f0.y + f1.y + f2.y + f3.y;
        acc.z += f0.z + f1.z + f2.z + f3.z;
        acc.w += f0.w + f1.w + f2.w + f3.w;
        i = 16;
    }
    for (; i < pcnt; i += 32) {
        int s0 = ci[i + 0],  s1 = ci[i + 4],  s2 = ci[i + 8],  s3 = ci[i + 12];
        int s4 = ci[i + 16], s5 = ci[i + 20], s6 = ci[i + 24], s7 = ci[i + 28];
        ushort4 a0 = *(const ushort4*)&hs[(size_t)s0 * 64 + cq * 4];
        ushort4 a1 = *(const ushort4*)&hs[(size_t)s1 * 64 + cq * 4];
        ushort4 a2 = *(const ushort4*)&hs[(size_t)s2 * 64 + cq * 4];
        ushort4 a3 = *(const ushort4*)&hs[(size_t)s3 * 64 + cq * 4];
        ushort4 a4 = *(const ushort4*)&hs[(size_t)s4 * 64 + cq * 4];
        ushort4 a5 = *(const ushort4*)&hs[(size_t)s5 * 64 + cq * 4];
        ushort4 a6 = *(const ushort4*)&hs[(size_t)s6 * 64 + cq * 4];
        ushort4 a7 = *(const ushort4*)&hs[(size_t)s7 * 64 + cq * 4];
        float4 f0 = bf4(a0), f1 = bf4(a1), f2 = bf4(a2), f3 = bf4(a3);
        float4 f4 = bf4(a4), f5 = bf4(a5), f6 = bf4(a6), f7 = bf4(a7);
        acc.x += (f0.x + f1.x) + (f2.x + f3.x) + (f4.x + f5.x) + (f6.x + f7.x);
        acc.y += (f0.y + f1.y) + (f2.y + f3.y) + (f4.y + f5.y) + (f6.y + f7.y);
        acc.z += (f0.z + f1.z) + (f2.z + f3.z) + (f4.z + f5.z) + (f6.z + f7.z);
        acc.w += (f0.w + f1.w) + (f2.w + f3.w) + (f4.w + f5.w) + (f6.w + f7.w);
    }

    acc.x += __shfl_xor(acc.x, 16, 64);
    acc.y += __shfl_xor(acc.y, 16, 64);
    acc.z += __shfl_xor(acc.z, 16, 64);
    acc.w += __shfl_xor(acc.w, 16, 64);
    acc.x += __shfl_xor(acc.x, 32, 64);
    acc.y += __shfl_xor(acc.y, 32, 64);
    acc.z += __shfl_xor(acc.z, 32, 64);
    acc.w += __shfl_xor(acc.w, 32, 64);

    if (eslot == 0) {
        ushort4 sv = *(const ushort4*)&hs[(size_t)node * 64 + cq * 4];
        float4 sf = bf4(sv);
        float dn = dis[node];
        float4 bb = *(const float4*)&bias[cq * 4];
        ushort4 o;
        o.x = f2bf(dn * (acc.x + sf.x) + bb.x);
        o.y = f2bf(dn * (acc.y + sf.y) + bb.y);
        o.z = f2bf(dn * (acc.z + sf.z) + bb.z);
        o.w = f2bf(dn * (acc.w + sf.w) + bb.w);
        *(ushort4*)&outp[(size_t)node * 64 + cq * 4] = o;
    }
}

// Fused mean-pool + FC head: one wave per graph. Binary-search the graph's
// node range in sorted batch, stream-sum its bf16 rows, then 64x10 matvec.
__global__ __launch_bounds__(64) void k_head2(const unsigned short* __restrict__ h,
                                              const int* __restrict__ batch,
                                              const float* __restrict__ Wfc,
                                              const float* __restrict__ bfc,
                                              float* __restrict__ out, int N) {
    __shared__ float p[64];
    int g = blockIdx.x, t = threadIdx.x;
    int lo = 0, hi = N;
    while (lo < hi) { int mid = (lo + hi) >> 1; if (batch[mid] < g) lo = mid + 1; else hi = mid; }
    int s = lo;
    hi = N;
    while (lo < hi) { int mid = (lo + hi) >> 1; if (batch[mid] < g + 1) lo = mid + 1; else hi = mid; }
    int e = lo;
    float acc = 0.f;
    int n = s;
    for (; n + 4 <= e; n += 4) {
        float a0 = bf2f(h[(size_t)(n + 0) * 64 + t]);
        float a1 = bf2f(h[(size_t)(n + 1) * 64 + t]);
        float a2 = bf2f(h[(size_t)(n + 2) * 64 + t]);
        float a3 = bf2f(h[(size_t)(n + 3) * 64 + t]);
        acc += (a0 + a1) + (a2 + a3);
    }
    for (; n < e; ++n) acc += bf2f(h[(size_t)n * 64 + t]);
    float cnt = (float)max(e - s, 1);
    p[t] = acc / cnt;
    __syncthreads();
    if (t < 10) {
        float o = bfc[t];
#pragma unroll
        for (int hh = 0; hh < 64; ++hh) o += p[hh] * Wfc[hh * 10 + t];
        out[g * 10 + t] = o;
    }
}

extern "C" void kernel_launch(void* const* d_in, const int* in_sizes, int n_in,
                              void* d_out, int out_size, void* d_ws, size_t ws_size,
                              hipStream_t stream) {
    const float* x = (const float*)d_in[0];
    const int* eidx = (const int*)d_in[1];
    const int* batch = (const int*)d_in[2];
    const float* W1 = (const float*)d_in[3];
    const float* b1 = (const float*)d_in[4];
    const float* W2 = (const float*)d_in[5];
    const float* b2 = (const float*)d_in[6];
    const float* W3 = (const float*)d_in[7];
    const float* b3 = (const float*)d_in[8];
    const float* Wfc = (const float*)d_in[9];
    const float* bfc = (const float*)d_in[10];
    float* out = (float*)d_out;

    const int N = in_sizes[0] / 128;  // 100000
    const int E = in_sizes[1] / 2;    // 3200000
    const int G = out_size / 10;      // 512
    const int NB = (N + 127) / 128;   // 782
    const int chunk = (E + NBLK - 1) / NBLK;

    char* ws = (char*)d_ws;
    size_t off = 0;
    auto alloc = [&](size_t bytes) -> char* {
        char* p = ws + off;
        off = (off + bytes + 511) & ~(size_t)511;
        return p;
    };
    int* deg = (int*)alloc((size_t)N * 4);
    int* rowptr = (int*)alloc((size_t)N * 4);
    float* dis = (float*)alloc((size_t)N * 4);
    int* starts = (int*)alloc((size_t)(MAXNB + 1) * 4);
    int* btotal = (int*)alloc((size_t)MAXNB * 4);
    int* blockhist = (int*)alloc((size_t)NB * NBLK * 4);
    unsigned int* epart = (unsigned int*)alloc((size_t)E * 4);
    int* colidx = (int*)alloc(((size_t)E + (size_t)NB * BPAD) * 4);
    unsigned short* hsA = (unsigned short*)alloc((size_t)(N + 1) * 64 * 2);
    unsigned short* hsB = (unsigned short*)alloc((size_t)(N + 1) * 64 * 2);
    unsigned short* obufb = (unsigned short*)alloc((size_t)N * 64 * 2);

    const int* esrc = eidx;
    const int* edst = eidx + E;

    k_hist<<<NBLK, 256, 0, stream>>>(edst, blockhist, E, chunk, NB);
    k_bscan<<<NB, 256, 0, stream>>>(blockhist, btotal);
    k_sscan<<<1, 256, 0, stream>>>(btotal, starts, NB, hsA, hsB, N);
    k_part<<<NBLK, 256, 0, stream>>>(esrc, edst, blockhist, starts, epart, E, chunk, NB);
    k_fine<<<NB, 256, 0, stream>>>(epart, starts, deg, rowptr, dis, colidx, N);

    int gblk = (N + 63) / 64;
    k_gemm_mfma<128><<<gblk, 256, 0, stream>>>(x, W1, dis, hsA, N);
    k_aggemm<<<gblk, 256, 0, stream>>>(hsA, rowptr, deg, colidx, dis, b1, W2, hsB, N);
    k_aggemm<<<gblk, 256, 0, stream>>>(hsB, rowptr, deg, colidx, dis, b2, W3, hsA, N);
    k_agg3<<<(N + 3) / 4, 256, 0, stream>>>(hsA, rowptr, deg, colidx, dis, b3, obufb, N);

    k_head2<<<G, 64, 0, stream>>>(obufb, batch, Wfc, bfc, out, N);
}

// Round 9
// 405.319 us; speedup vs baseline: 1.0742x; 1.0742x over previous
//
#include <hip/hip_runtime.h>
#include <hip/hip_bf16.h>

// ---------------------------------------------------------------------------
// GCN forward: hierarchical atomic-free CSR build (16-padded per-node lists)
// -> 3x (MFMA-bf16 GEMM w/ fused dis-scale + bf16 store -> padded colidx
// gather aggregate) -> fused pool+FC head.
// hs = dis[n]*h[n] in bf16 (+zero dummy row N). Inter-layer obuf is bf16.
// k_agg lane map: eslot(0..7) x ch-octet(0..7); each gather = uint4 (16B,
// 8 bf16 channels) -> 8 edges per VMEM instruction; butterfly over eslot.
// NOTE (R5 lesson): NO float LDS atomics — CAS loop, ~20x cost.
// NOTE (R8 lesson): do NOT fuse gather into the GEMM tile kernel — the agg
// needs one-wave-per-node TLP (25k blocks); fusion dropped occupancy 69->40%
// and regressed 55->85us.
// ---------------------------------------------------------------------------

#define NBLK 1024       // partition blocks (1 block/CU was grid-limited at 256)
#define MAXNB 1024      // max buckets supported (N <= 131072)
#define FCAP 4608       // LDS edge-staging capacity in k_fine
#define BPAD 2048       // per-bucket colidx padding slack

typedef __attribute__((ext_vector_type(8))) short short8;    // 8 bf16 (4 VGPR)
typedef __attribute__((ext_vector_type(4))) float floatx4;   // MFMA acc

__device__ __forceinline__ float bf2f(unsigned short v) {
    return __uint_as_float(((unsigned int)v) << 16);
}
__device__ __forceinline__ unsigned short f2bf(float x) {
    __hip_bfloat16 b = __float2bfloat16(x);  // round-to-nearest
    return *(unsigned short*)&b;
}
// accumulate 8 bf16 (packed uint4) into 8 fp32
__device__ __forceinline__ void acc8(float* a, uint4 u) {
    a[0] += __uint_as_float(u.x << 16);
    a[1] += __uint_as_float(u.x & 0xFFFF0000u);
    a[2] += __uint_as_float(u.y << 16);
    a[3] += __uint_as_float(u.y & 0xFFFF0000u);
    a[4] += __uint_as_float(u.z << 16);
    a[5] += __uint_as_float(u.z & 0xFFFF0000u);
    a[6] += __uint_as_float(u.w << 16);
    a[7] += __uint_as_float(u.w & 0xFFFF0000u);
}
__device__ __forceinline__ void unp8(float* f, uint4 u) {
    f[0] = __uint_as_float(u.x << 16);
    f[1] = __uint_as_float(u.x & 0xFFFF0000u);
    f[2] = __uint_as_float(u.y << 16);
    f[3] = __uint_as_float(u.y & 0xFFFF0000u);
    f[4] = __uint_as_float(u.z << 16);
    f[5] = __uint_as_float(u.z & 0xFFFF0000u);
    f[6] = __uint_as_float(u.w << 16);
    f[7] = __uint_as_float(u.w & 0xFFFF0000u);
}

// P1: per-block bucket histogram (int4-vectorized edge reads).
__global__ __launch_bounds__(256) void k_hist(const int* __restrict__ dst,
                                              int* __restrict__ blockhist,
                                              int E, int chunk, int nb) {
    __shared__ int h[MAXNB];
    int b = blockIdx.x, t = threadIdx.x;
    for (int j = t; j < nb; j += 256) h[j] = 0;
    __syncthreads();
    int lo = b * chunk, hi = min(lo + chunk, E);
    int m = hi - lo;
    if (m < 0) m = 0;
    int nv = m >> 2;
    const int4* d4 = (const int4*)(dst + lo);
    for (int i = t; i < nv; i += 256) {
        int4 v = d4[i];
        atomicAdd(&h[v.x >> 7], 1);
        atomicAdd(&h[v.y >> 7], 1);
        atomicAdd(&h[v.z >> 7], 1);
        atomicAdd(&h[v.w >> 7], 1);
    }
    for (int i = lo + (nv << 2) + t; i < hi; i += 256) atomicAdd(&h[dst[i] >> 7], 1);
    __syncthreads();
    for (int j = t; j < nb; j += 256) blockhist[j * NBLK + b] = h[j];
}

// P2a: per-bucket exclusive scan over NBLK=1024 blocks (4 elems/thread).
__global__ __launch_bounds__(256) void k_bscan(int* __restrict__ blockhist,
                                               int* __restrict__ btotal) {
    __shared__ int sm[256];
    int j = blockIdx.x, t = threadIdx.x;
    int base = j * NBLK + t * 4;
    int v0 = blockhist[base + 0];
    int v1 = blockhist[base + 1];
    int v2 = blockhist[base + 2];
    int v3 = blockhist[base + 3];
    int tsum = v0 + v1 + v2 + v3;
    sm[t] = tsum;
    __syncthreads();
    for (int d = 1; d < 256; d <<= 1) {
        int u = (t >= d) ? sm[t - d] : 0;
        __syncthreads();
        sm[t] += u;
        __syncthreads();
    }
    int excl = sm[t] - tsum;
    blockhist[base + 0] = excl;
    blockhist[base + 1] = excl + v0;
    blockhist[base + 2] = excl + v0 + v1;
    blockhist[base + 3] = excl + v0 + v1 + v2;
    if (t == 255) btotal[j] = sm[255];
}

// P2b: single-block exclusive scan of bucket totals -> starts[0..nb].
// Also zeroes the dummy hs rows (index N) of both ping-pong buffers.
__global__ __launch_bounds__(256) void k_sscan(const int* __restrict__ btotal,
                                               int* __restrict__ starts, int nb,
                                               unsigned short* __restrict__ z1,
                                               unsigned short* __restrict__ z2,
                                               int N) {
    __shared__ int sm[256];
    int t = threadIdx.x;
    if (t < 64) {
        z1[(size_t)N * 64 + t] = 0;
        z2[(size_t)N * 64 + t] = 0;
    }
    int base = t * 4;
    int v0 = (base + 0 < nb) ? btotal[base + 0] : 0;
    int v1 = (base + 1 < nb) ? btotal[base + 1] : 0;
    int v2 = (base + 2 < nb) ? btotal[base + 2] : 0;
    int v3 = (base + 3 < nb) ? btotal[base + 3] : 0;
    int tsum = v0 + v1 + v2 + v3;
    sm[t] = tsum;
    __syncthreads();
    for (int d = 1; d < 256; d <<= 1) {
        int u = (t >= d) ? sm[t - d] : 0;
        __syncthreads();
        sm[t] += u;
        __syncthreads();
    }
    int excl = sm[t] - tsum;
    if (base + 0 < nb) starts[base + 0] = excl;
    if (base + 1 < nb) starts[base + 1] = excl + v0;
    if (base + 2 < nb) starts[base + 2] = excl + v0 + v1;
    if (base + 3 < nb) starts[base + 3] = excl + v0 + v1 + v2;
    if (t == 255) starts[nb] = sm[255];
}

// P3: partition edges into bucket regions. epart = src | (dst&127)<<17.
__global__ __launch_bounds__(256) void k_part(const int* __restrict__ src,
                                              const int* __restrict__ dst,
                                              const int* __restrict__ blockhist,
                                              const int* __restrict__ starts,
                                              unsigned int* __restrict__ epart,
                                              int E, int chunk, int nb) {
    __shared__ int cur[MAXNB];
    int b = blockIdx.x, t = threadIdx.x;
    for (int j = t; j < nb; j += 256) cur[j] = starts[j] + blockhist[j * NBLK + b];
    __syncthreads();
    int lo = b * chunk, hi = min(lo + chunk, E);
    int m = hi - lo;
    if (m < 0) m = 0;
    int nv = m >> 2;
    const int4* d4 = (const int4*)(dst + lo);
    const int4* s4 = (const int4*)(src + lo);
    for (int i = t; i < nv; i += 256) {
        int4 d = d4[i];
        int4 s = s4[i];
        int p;
        p = atomicAdd(&cur[d.x >> 7], 1); epart[p] = (unsigned int)s.x | ((unsigned int)(d.x & 127) << 17);
        p = atomicAdd(&cur[d.y >> 7], 1); epart[p] = (unsigned int)s.y | ((unsigned int)(d.y & 127) << 17);
        p = atomicAdd(&cur[d.z >> 7], 1); epart[p] = (unsigned int)s.z | ((unsigned int)(d.z & 127) << 17);
        p = atomicAdd(&cur[d.w >> 7], 1); epart[p] = (unsigned int)s.w | ((unsigned int)(d.w & 127) << 17);
    }
    for (int i = lo + (nv << 2) + t; i < hi; i += 256) {
        int d = dst[i];
        int pos = atomicAdd(&cur[d >> 7], 1);
        epart[pos] = (unsigned int)src[i] | ((unsigned int)(d & 127) << 17);
    }
}

// P4: per-bucket fine sort with padded per-node lists (pad src = N).
__global__ __launch_bounds__(256) void k_fine(const unsigned int* __restrict__ epart,
                                              const int* __restrict__ starts,
                                              int* __restrict__ deg,
                                              int* __restrict__ rowptr,
                                              float* __restrict__ dis,
                                              int* __restrict__ colidx, int N) {
    __shared__ unsigned int eb[FCAP];
    __shared__ int cnt[128], sc[128], cur[128];
    int j = blockIdx.x, t = threadIdx.x;
    int n0 = j << 7;
    int nn = min(128, N - n0);
    int s = starts[j], e = starts[j + 1];
    int m = e - s;
    int pbase = s + j * BPAD;
    if (t < 128) cnt[t] = 0;
    __syncthreads();
    for (int i = t; i < m; i += 256) {
        unsigned int p = epart[s + i];
        if (i < FCAP) eb[i] = p;
        atomicAdd(&cnt[p >> 17], 1);
    }
    __syncthreads();
    int pcv = 0;
    if (t < 128) { pcv = (cnt[t] + 15) & ~15; sc[t] = pcv; }
    __syncthreads();
    for (int d = 1; d < 128; d <<= 1) {
        int u = (t < 128 && t >= d) ? sc[t - d] : 0;
        __syncthreads();
        if (t < 128) sc[t] += u;
        __syncthreads();
    }
    if (t < nn) {
        int c = cnt[t];
        int rp = pbase + sc[t] - pcv;
        deg[n0 + t] = c;
        rowptr[n0 + t] = rp;
        dis[n0 + t] = rsqrtf((float)c + 1.0f);
        cur[t] = rp;
    }
    __syncthreads();
    for (int i = t; i < m; i += 256) {
        unsigned int p = (i < FCAP) ? eb[i] : epart[s + i];
        int pos = atomicAdd(&cur[p >> 17], 1);
        colidx[pos] = (int)(p & 0x1FFFF);
    }
    __syncthreads();
    if (t < nn) {
        int endp = rowptr[n0 + t] + ((cnt[t] + 15) & ~15);
        for (int q = cur[t]; q < endp; ++q) colidx[q] = N;  // dummy row
    }
}

// MFMA GEMM: C[64x64] per block = A[64xK] * W[Kx64]; bf16 inputs, fp32 acc.
// Epilogue scales by dis[row], stores bf16 hs. ABF16: A already bf16.
template <int K, int ABF16>
__global__ __launch_bounds__(256) void k_gemm_mfma(const void* __restrict__ Ap,
                                                   const float* __restrict__ W,
                                                   const float* __restrict__ dis,
                                                   unsigned short* __restrict__ hs,
                                                   int N) {
    constexpr int AS = K + 8;
    __shared__ unsigned short As[64 * AS];
    __shared__ unsigned short Bt[64 * AS];
    const int tid = threadIdx.x;
    const int r0 = blockIdx.x * 64;

    for (int idx = tid; idx < K * 64; idx += 256) {
        int k = idx >> 6, n = idx & 63;
        Bt[n * AS + k] = f2bf(W[idx]);
    }
    if (ABF16) {
        const unsigned short* A = (const unsigned short*)Ap;
        for (int idx = tid; idx < 64 * (K / 8); idx += 256) {
            int row = idx / (K / 8), c8 = idx % (K / 8);
            int gr = r0 + row;
            uint4 v = (gr < N) ? *(const uint4*)&A[(size_t)gr * K + c8 * 8]
                               : make_uint4(0u, 0u, 0u, 0u);
            *(uint4*)&As[row * AS + c8 * 8] = v;
        }
    } else {
        const float* A = (const float*)Ap;
        for (int idx = tid; idx < 64 * (K / 4); idx += 256) {
            int row = idx / (K / 4), kq = idx % (K / 4);
            int gr = r0 + row;
            float4 a = (gr < N) ? ((const float4*)(A + (size_t)gr * K))[kq]
                                : make_float4(0.f, 0.f, 0.f, 0.f);
            ushort4 v;
            v.x = f2bf(a.x); v.y = f2bf(a.y); v.z = f2bf(a.z); v.w = f2bf(a.w);
            *(ushort4*)&As[row * AS + kq * 4] = v;
        }
    }
    __syncthreads();

    const int w = tid >> 6, lane = tid & 63;
    const int m = lane & 15, quad = lane >> 4;
    floatx4 acc0 = {0.f, 0.f, 0.f, 0.f};
    floatx4 acc1 = {0.f, 0.f, 0.f, 0.f};
    floatx4 acc2 = {0.f, 0.f, 0.f, 0.f};
    floatx4 acc3 = {0.f, 0.f, 0.f, 0.f};
#pragma unroll
    for (int s = 0; s < K / 32; ++s) {
        int ko = s * 32 + quad * 8;
        short8 a  = *(const short8*)&As[(w * 16 + m) * AS + ko];
        short8 b0 = *(const short8*)&Bt[(0 * 16 + m) * AS + ko];
        short8 b1 = *(const short8*)&Bt[(1 * 16 + m) * AS + ko];
        short8 b2 = *(const short8*)&Bt[(2 * 16 + m) * AS + ko];
        short8 b3 = *(const short8*)&Bt[(3 * 16 + m) * AS + ko];
        acc0 = __builtin_amdgcn_mfma_f32_16x16x32_bf16(a, b0, acc0, 0, 0, 0);
        acc1 = __builtin_amdgcn_mfma_f32_16x16x32_bf16(a, b1, acc1, 0, 0, 0);
        acc2 = __builtin_amdgcn_mfma_f32_16x16x32_bf16(a, b2, acc2, 0, 0, 0);
        acc3 = __builtin_amdgcn_mfma_f32_16x16x32_bf16(a, b3, acc3, 0, 0, 0);
    }
#pragma unroll
    for (int r = 0; r < 4; ++r) {
        int gr = r0 + w * 16 + quad * 4 + r;
        if (gr < N) {
            float dn = dis[gr];
            size_t base = (size_t)gr * 64 + m;
            hs[base + 0]  = f2bf(acc0[r] * dn);
            hs[base + 16] = f2bf(acc1[r] * dn);
            hs[base + 32] = f2bf(acc2[r] * dn);
            hs[base + 48] = f2bf(acc3[r] * dn);
        }
    }
}

// One wave per node. lane = eslot(0..7) x ch-octet(0..7). Each gather is a
// 16B uint4 (8 bf16 channels) -> 8 edges per VMEM instruction. Padded x16
// lists (dummy src=N). Butterfly over eslot (masks 8,16,32). bf16 out.
template <int RELU>
__global__ __launch_bounds__(256) void k_agg(const unsigned short* __restrict__ hs,
                                             const int* __restrict__ rowptr,
                                             const int* __restrict__ deg,
                                             const int* __restrict__ colidx,
                                             const float* __restrict__ dis,
                                             const float* __restrict__ bias,
                                             unsigned short* __restrict__ outp,
                                             int N) {
    int node = blockIdx.x * 4 + (threadIdx.x >> 6);
    if (node >= N) return;
    int lane = threadIdx.x & 63;
    int eslot = lane >> 3;   // 0..7
    int cq = lane & 7;       // channel octet: channels cq*8 .. cq*8+7

    int start = rowptr[node];
    int cnt = deg[node];
    int pcnt = (cnt + 15) & ~15;
    const int* ci = colidx + start + eslot;
    float acc[8] = {0.f, 0.f, 0.f, 0.f, 0.f, 0.f, 0.f, 0.f};

    int i = 0;
    if (pcnt & 16) {
        int s0 = ci[0], s1 = ci[8];
        uint4 a0 = *(const uint4*)&hs[(size_t)s0 * 64 + cq * 8];
        uint4 a1 = *(const uint4*)&hs[(size_t)s1 * 64 + cq * 8];
        acc8(acc, a0);
        acc8(acc, a1);
        i = 16;
    }
    for (; i < pcnt; i += 32) {
        int s0 = ci[i + 0], s1 = ci[i + 8], s2 = ci[i + 16], s3 = ci[i + 24];
        uint4 a0 = *(const uint4*)&hs[(size_t)s0 * 64 + cq * 8];
        uint4 a1 = *(const uint4*)&hs[(size_t)s1 * 64 + cq * 8];
        uint4 a2 = *(const uint4*)&hs[(size_t)s2 * 64 + cq * 8];
        uint4 a3 = *(const uint4*)&hs[(size_t)s3 * 64 + cq * 8];
        acc8(acc, a0);
        acc8(acc, a1);
        acc8(acc, a2);
        acc8(acc, a3);
    }

#pragma unroll
    for (int c = 0; c < 8; ++c) {
        acc[c] += __shfl_xor(acc[c], 8, 64);
        acc[c] += __shfl_xor(acc[c], 16, 64);
        acc[c] += __shfl_xor(acc[c], 32, 64);
    }

    if (eslot == 0) {
        uint4 sv = *(const uint4*)&hs[(size_t)node * 64 + cq * 8];
        float sf[8];
        unp8(sf, sv);
        float dn = dis[node];
        float4 blo = *(const float4*)&bias[cq * 8];
        float4 bhi = *(const float4*)&bias[cq * 8 + 4];
        float bb[8] = {blo.x, blo.y, blo.z, blo.w, bhi.x, bhi.y, bhi.z, bhi.w};
        unsigned short o[8];
#pragma unroll
        for (int c = 0; c < 8; ++c) {
            float v = dn * (acc[c] + sf[c]) + bb[c];
            if (RELU) v = fmaxf(v, 0.f);
            o[c] = f2bf(v);
        }
        uint4 ov;
        ov.x = (unsigned int)o[0] | ((unsigned int)o[1] << 16);
        ov.y = (unsigned int)o[2] | ((unsigned int)o[3] << 16);
        ov.z = (unsigned int)o[4] | ((unsigned int)o[5] << 16);
        ov.w = (unsigned int)o[6] | ((unsigned int)o[7] << 16);
        *(uint4*)&outp[(size_t)node * 64 + cq * 8] = ov;
    }
}

// Fused mean-pool + FC head: one wave per graph (binary-search node range in
// sorted batch, stream-sum bf16 rows, 64x10 matvec).
__global__ __launch_bounds__(64) void k_head2(const unsigned short* __restrict__ h,
                                              const int* __restrict__ batch,
                                              const float* __restrict__ Wfc,
                                              const float* __restrict__ bfc,
                                              float* __restrict__ out, int N) {
    __shared__ float p[64];
    int g = blockIdx.x, t = threadIdx.x;
    int lo = 0, hi = N;
    while (lo < hi) { int mid = (lo + hi) >> 1; if (batch[mid] < g) lo = mid + 1; else hi = mid; }
    int s = lo;
    hi = N;
    while (lo < hi) { int mid = (lo + hi) >> 1; if (batch[mid] < g + 1) lo = mid + 1; else hi = mid; }
    int e = lo;
    float acc = 0.f;
    int n = s;
    for (; n + 4 <= e; n += 4) {
        float a0 = bf2f(h[(size_t)(n + 0) * 64 + t]);
        float a1 = bf2f(h[(size_t)(n + 1) * 64 + t]);
        float a2 = bf2f(h[(size_t)(n + 2) * 64 + t]);
        float a3 = bf2f(h[(size_t)(n + 3) * 64 + t]);
        acc += (a0 + a1) + (a2 + a3);
    }
    for (; n < e; ++n) acc += bf2f(h[(size_t)n * 64 + t]);
    float cnt = (float)max(e - s, 1);
    p[t] = acc / cnt;
    __syncthreads();
    if (t < 10) {
        float o = bfc[t];
#pragma unroll
        for (int hh = 0; hh < 64; ++hh) o += p[hh] * Wfc[hh * 10 + t];
        out[g * 10 + t] = o;
    }
}

extern "C" void kernel_launch(void* const* d_in, const int* in_sizes, int n_in,
                              void* d_out, int out_size, void* d_ws, size_t ws_size,
                              hipStream_t stream) {
    const float* x = (const float*)d_in[0];
    const int* eidx = (const int*)d_in[1];
    const int* batch = (const int*)d_in[2];
    const float* W1 = (const float*)d_in[3];
    const float* b1 = (const float*)d_in[4];
    const float* W2 = (const float*)d_in[5];
    const float* b2 = (const float*)d_in[6];
    const float* W3 = (const float*)d_in[7];
    const float* b3 = (const float*)d_in[8];
    const float* Wfc = (const float*)d_in[9];
    const float* bfc = (const float*)d_in[10];
    float* out = (float*)d_out;

    const int N = in_sizes[0] / 128;  // 100000
    const int E = in_sizes[1] / 2;    // 3200000
    const int G = out_size / 10;      // 512
    const int NB = (N + 127) / 128;   // 782
    int chunk = ((E + NBLK - 1) / NBLK + 3) & ~3;  // 16B-aligned chunk starts

    char* ws = (char*)d_ws;
    size_t off = 0;
    auto alloc = [&](size_t bytes) -> char* {
        char* p = ws + off;
        off = (off + bytes + 511) & ~(size_t)511;
        return p;
    };
    int* deg = (int*)alloc((size_t)N * 4);
    int* rowptr = (int*)alloc((size_t)N * 4);
    float* dis = (float*)alloc((size_t)N * 4);
    int* starts = (int*)alloc((size_t)(MAXNB + 1) * 4);
    int* btotal = (int*)alloc((size_t)MAXNB * 4);
    int* blockhist = (int*)alloc((size_t)NB * NBLK * 4);
    unsigned int* epart = (unsigned int*)alloc((size_t)E * 4);
    int* colidx = (int*)alloc(((size_t)E + (size_t)NB * BPAD) * 4);
    unsigned short* hsA = (unsigned short*)alloc((size_t)(N + 1) * 64 * 2);
    unsigned short* hsB = (unsigned short*)alloc((size_t)(N + 1) * 64 * 2);
    unsigned short* obufb = (unsigned short*)alloc((size_t)N * 64 * 2);

    const int* esrc = eidx;
    const int* edst = eidx + E;

    k_hist<<<NBLK, 256, 0, stream>>>(edst, blockhist, E, chunk, NB);
    k_bscan<<<NB, 256, 0, stream>>>(blockhist, btotal);
    k_sscan<<<1, 256, 0, stream>>>(btotal, starts, NB, hsA, hsB, N);
    k_part<<<NBLK, 256, 0, stream>>>(esrc, edst, blockhist, starts, epart, E, chunk, NB);
    k_fine<<<NB, 256, 0, stream>>>(epart, starts, deg, rowptr, dis, colidx, N);

    int gblk = (N + 63) / 64;
    k_gemm_mfma<128, 0><<<gblk, 256, 0, stream>>>(x, W1, dis, hsA, N);
    k_agg<1><<<(N + 3) / 4, 256, 0, stream>>>(hsA, rowptr, deg, colidx, dis, b1, obufb, N);
    k_gemm_mfma<64, 1><<<gblk, 256, 0, stream>>>(obufb, W2, dis, hsB, N);
    k_agg<1><<<(N + 3) / 4, 256, 0, stream>>>(hsB, rowptr, deg, colidx, dis, b2, obufb, N);
    k_gemm_mfma<64, 1><<<gblk, 256, 0, stream>>>(obufb, W3, dis, hsA, N);
    k_agg<0><<<(N + 3) / 4, 256, 0, stream>>>(hsA, rowptr, deg, colidx, dis, b3, obufb, N);

    k_head2<<<G, 64, 0, stream>>>(obufb, batch, Wfc, bfc, out, N);
}

// Round 10
// 382.703 us; speedup vs baseline: 1.1377x; 1.0591x over previous
//
#include <hip/hip_runtime.h>
#include <hip/hip_bf16.h>

// ---------------------------------------------------------------------------
// GCN forward: hierarchical atomic-free CSR build (256-node buckets,
// 16-padded per-node lists) -> 3x (MFMA-bf16 GEMM w/ fused dis-scale + bf16
// store -> padded colidx gather aggregate) -> fused pool+FC head.
// hs = dis[n]*h[n] in bf16 (+zero dummy row N). Inter-layer bufs bf16.
// k_agg lane map: eslot(0..7) x ch-octet(0..7); 16B uint4 gathers -> 8 edges
// per VMEM instruction; butterfly over eslot.
// NOTE (R5): NO float LDS atomics — CAS loop, ~20x cost.
// NOTE (R8): do NOT fuse gather into GEMM tile — needs one-wave-per-node TLP.
// NOTE (R9): NBLK=1024 regressed build (short scatter runs + 4x blockhist);
// 256 partition blocks + 256-node buckets maximize scatter run length.
// ---------------------------------------------------------------------------

#define NBLK 256        // partition blocks
#define MAXNB 512       // max buckets (N <= 131072 at 256 nodes/bucket)
#define FCAP 9216       // LDS edge-staging capacity in k_fine (36 KB)
#define BPAD 4096       // per-bucket colidx padding slack (256 * 15 max)

typedef __attribute__((ext_vector_type(8))) short short8;    // 8 bf16 (4 VGPR)
typedef __attribute__((ext_vector_type(4))) float floatx4;   // MFMA acc

__device__ __forceinline__ float bf2f(unsigned short v) {
    return __uint_as_float(((unsigned int)v) << 16);
}
__device__ __forceinline__ unsigned short f2bf(float x) {
    __hip_bfloat16 b = __float2bfloat16(x);  // round-to-nearest
    return *(unsigned short*)&b;
}
// accumulate 8 bf16 (packed uint4) into 8 fp32
__device__ __forceinline__ void acc8(float* a, uint4 u) {
    a[0] += __uint_as_float(u.x << 16);
    a[1] += __uint_as_float(u.x & 0xFFFF0000u);
    a[2] += __uint_as_float(u.y << 16);
    a[3] += __uint_as_float(u.y & 0xFFFF0000u);
    a[4] += __uint_as_float(u.z << 16);
    a[5] += __uint_as_float(u.z & 0xFFFF0000u);
    a[6] += __uint_as_float(u.w << 16);
    a[7] += __uint_as_float(u.w & 0xFFFF0000u);
}
__device__ __forceinline__ void unp8(float* f, uint4 u) {
    f[0] = __uint_as_float(u.x << 16);
    f[1] = __uint_as_float(u.x & 0xFFFF0000u);
    f[2] = __uint_as_float(u.y << 16);
    f[3] = __uint_as_float(u.y & 0xFFFF0000u);
    f[4] = __uint_as_float(u.z << 16);
    f[5] = __uint_as_float(u.z & 0xFFFF0000u);
    f[6] = __uint_as_float(u.w << 16);
    f[7] = __uint_as_float(u.w & 0xFFFF0000u);
}

// P1: per-block bucket histogram (int4-vectorized edge reads). bucket = dst>>8.
__global__ __launch_bounds__(256) void k_hist(const int* __restrict__ dst,
                                              int* __restrict__ blockhist,
                                              int E, int chunk, int nb) {
    __shared__ int h[MAXNB];
    int b = blockIdx.x, t = threadIdx.x;
    for (int j = t; j < nb; j += 256) h[j] = 0;
    __syncthreads();
    int lo = b * chunk, hi = min(lo + chunk, E);
    int m = hi - lo;
    if (m < 0) m = 0;
    int nv = m >> 2;
    const int4* d4 = (const int4*)(dst + lo);
    for (int i = t; i < nv; i += 256) {
        int4 v = d4[i];
        atomicAdd(&h[v.x >> 8], 1);
        atomicAdd(&h[v.y >> 8], 1);
        atomicAdd(&h[v.z >> 8], 1);
        atomicAdd(&h[v.w >> 8], 1);
    }
    for (int i = lo + (nv << 2) + t; i < hi; i += 256) atomicAdd(&h[dst[i] >> 8], 1);
    __syncthreads();
    for (int j = t; j < nb; j += 256) blockhist[j * NBLK + b] = h[j];
}

// P2a: per-bucket exclusive scan over NBLK=256 blocks (in place); btotal[j].
__global__ __launch_bounds__(256) void k_bscan(int* __restrict__ blockhist,
                                               int* __restrict__ btotal) {
    __shared__ int sm[256];
    int j = blockIdx.x, t = threadIdx.x;
    int v = blockhist[j * NBLK + t];
    sm[t] = v;
    __syncthreads();
    for (int d = 1; d < 256; d <<= 1) {
        int u = (t >= d) ? sm[t - d] : 0;
        __syncthreads();
        sm[t] += u;
        __syncthreads();
    }
    blockhist[j * NBLK + t] = sm[t] - v;
    if (t == 255) btotal[j] = sm[255];
}

// P2b: single-block exclusive scan of bucket totals -> starts[0..nb].
// Also zeroes the dummy hs rows (index N) of both ping-pong buffers.
__global__ __launch_bounds__(256) void k_sscan(const int* __restrict__ btotal,
                                               int* __restrict__ starts, int nb,
                                               unsigned short* __restrict__ z1,
                                               unsigned short* __restrict__ z2,
                                               int N) {
    __shared__ int sm[256];
    int t = threadIdx.x;
    if (t < 64) {
        z1[(size_t)N * 64 + t] = 0;
        z2[(size_t)N * 64 + t] = 0;
    }
    int base = t * 2;
    int v0 = (base + 0 < nb) ? btotal[base + 0] : 0;
    int v1 = (base + 1 < nb) ? btotal[base + 1] : 0;
    int tsum = v0 + v1;
    sm[t] = tsum;
    __syncthreads();
    for (int d = 1; d < 256; d <<= 1) {
        int u = (t >= d) ? sm[t - d] : 0;
        __syncthreads();
        sm[t] += u;
        __syncthreads();
    }
    int excl = sm[t] - tsum;
    if (base + 0 < nb) starts[base + 0] = excl;
    if (base + 1 < nb) starts[base + 1] = excl + v0;
    if (t == 255) starts[nb] = sm[255];
}

// P3: partition edges into bucket regions. epart = src | (dst&255)<<17.
__global__ __launch_bounds__(256) void k_part(const int* __restrict__ src,
                                              const int* __restrict__ dst,
                                              const int* __restrict__ blockhist,
                                              const int* __restrict__ starts,
                                              unsigned int* __restrict__ epart,
                                              int E, int chunk, int nb) {
    __shared__ int cur[MAXNB];
    int b = blockIdx.x, t = threadIdx.x;
    for (int j = t; j < nb; j += 256) cur[j] = starts[j] + blockhist[j * NBLK + b];
    __syncthreads();
    int lo = b * chunk, hi = min(lo + chunk, E);
    int m = hi - lo;
    if (m < 0) m = 0;
    int nv = m >> 2;
    const int4* d4 = (const int4*)(dst + lo);
    const int4* s4 = (const int4*)(src + lo);
    for (int i = t; i < nv; i += 256) {
        int4 d = d4[i];
        int4 s = s4[i];
        int p;
        p = atomicAdd(&cur[d.x >> 8], 1); epart[p] = (unsigned int)s.x | ((unsigned int)(d.x & 255) << 17);
        p = atomicAdd(&cur[d.y >> 8], 1); epart[p] = (unsigned int)s.y | ((unsigned int)(d.y & 255) << 17);
        p = atomicAdd(&cur[d.z >> 8], 1); epart[p] = (unsigned int)s.z | ((unsigned int)(d.z & 255) << 17);
        p = atomicAdd(&cur[d.w >> 8], 1); epart[p] = (unsigned int)s.w | ((unsigned int)(d.w & 255) << 17);
    }
    for (int i = lo + (nv << 2) + t; i < hi; i += 256) {
        int d = dst[i];
        int pos = atomicAdd(&cur[d >> 8], 1);
        epart[pos] = (unsigned int)src[i] | ((unsigned int)(d & 255) << 17);
    }
}

// P4: per-bucket fine sort with padded per-node lists (pad src = N).
// 256 nodes per bucket; full 256-thread scan.
__global__ __launch_bounds__(256) void k_fine(const unsigned int* __restrict__ epart,
                                              const int* __restrict__ starts,
                                              int* __restrict__ deg,
                                              int* __restrict__ rowptr,
                                              float* __restrict__ dis,
                                              int* __restrict__ colidx, int N) {
    __shared__ unsigned int eb[FCAP];
    __shared__ int cnt[256], sc[256], cur[256];
    int j = blockIdx.x, t = threadIdx.x;
    int n0 = j << 8;
    int nn = min(256, N - n0);
    int s = starts[j], e = starts[j + 1];
    int m = e - s;
    int pbase = s + j * BPAD;
    cnt[t] = 0;
    __syncthreads();
    for (int i = t; i < m; i += 256) {
        unsigned int p = epart[s + i];
        if (i < FCAP) eb[i] = p;
        atomicAdd(&cnt[p >> 17], 1);
    }
    __syncthreads();
    int pcv = (cnt[t] + 15) & ~15;
    sc[t] = pcv;
    __syncthreads();
    for (int d = 1; d < 256; d <<= 1) {
        int u = (t >= d) ? sc[t - d] : 0;
        __syncthreads();
        sc[t] += u;
        __syncthreads();
    }
    if (t < nn) {
        int c = cnt[t];
        int rp = pbase + sc[t] - pcv;
        deg[n0 + t] = c;
        rowptr[n0 + t] = rp;
        dis[n0 + t] = rsqrtf((float)c + 1.0f);
        cur[t] = rp;
    }
    __syncthreads();
    for (int i = t; i < m; i += 256) {
        unsigned int p = (i < FCAP) ? eb[i] : epart[s + i];
        int pos = atomicAdd(&cur[p >> 17], 1);
        colidx[pos] = (int)(p & 0x1FFFF);
    }
    __syncthreads();
    if (t < nn) {
        int endp = rowptr[n0 + t] + ((cnt[t] + 15) & ~15);
        for (int q = cur[t]; q < endp; ++q) colidx[q] = N;  // dummy row
    }
}

// MFMA GEMM: C[64x64] per block = A[64xK] * W[Kx64]; bf16 inputs, fp32 acc.
// Epilogue scales by dis[row], stores bf16 hs. ABF16: A already bf16.
template <int K, int ABF16>
__global__ __launch_bounds__(256) void k_gemm_mfma(const void* __restrict__ Ap,
                                                   const float* __restrict__ W,
                                                   const float* __restrict__ dis,
                                                   unsigned short* __restrict__ hs,
                                                   int N) {
    constexpr int AS = K + 8;
    __shared__ unsigned short As[64 * AS];
    __shared__ unsigned short Bt[64 * AS];
    const int tid = threadIdx.x;
    const int r0 = blockIdx.x * 64;

    for (int idx = tid; idx < K * 64; idx += 256) {
        int k = idx >> 6, n = idx & 63;
        Bt[n * AS + k] = f2bf(W[idx]);
    }
    if (ABF16) {
        const unsigned short* A = (const unsigned short*)Ap;
        for (int idx = tid; idx < 64 * (K / 8); idx += 256) {
            int row = idx / (K / 8), c8 = idx % (K / 8);
            int gr = r0 + row;
            uint4 v = (gr < N) ? *(const uint4*)&A[(size_t)gr * K + c8 * 8]
                               : make_uint4(0u, 0u, 0u, 0u);
            *(uint4*)&As[row * AS + c8 * 8] = v;
        }
    } else {
        const float* A = (const float*)Ap;
        for (int idx = tid; idx < 64 * (K / 4); idx += 256) {
            int row = idx / (K / 4), kq = idx % (K / 4);
            int gr = r0 + row;
            float4 a = (gr < N) ? ((const float4*)(A + (size_t)gr * K))[kq]
                                : make_float4(0.f, 0.f, 0.f, 0.f);
            ushort4 v;
            v.x = f2bf(a.x); v.y = f2bf(a.y); v.z = f2bf(a.z); v.w = f2bf(a.w);
            *(ushort4*)&As[row * AS + kq * 4] = v;
        }
    }
    __syncthreads();

    const int w = tid >> 6, lane = tid & 63;
    const int m = lane & 15, quad = lane >> 4;
    floatx4 acc0 = {0.f, 0.f, 0.f, 0.f};
    floatx4 acc1 = {0.f, 0.f, 0.f, 0.f};
    floatx4 acc2 = {0.f, 0.f, 0.f, 0.f};
    floatx4 acc3 = {0.f, 0.f, 0.f, 0.f};
#pragma unroll
    for (int s = 0; s < K / 32; ++s) {
        int ko = s * 32 + quad * 8;
        short8 a  = *(const short8*)&As[(w * 16 + m) * AS + ko];
        short8 b0 = *(const short8*)&Bt[(0 * 16 + m) * AS + ko];
        short8 b1 = *(const short8*)&Bt[(1 * 16 + m) * AS + ko];
        short8 b2 = *(const short8*)&Bt[(2 * 16 + m) * AS + ko];
        short8 b3 = *(const short8*)&Bt[(3 * 16 + m) * AS + ko];
        acc0 = __builtin_amdgcn_mfma_f32_16x16x32_bf16(a, b0, acc0, 0, 0, 0);
        acc1 = __builtin_amdgcn_mfma_f32_16x16x32_bf16(a, b1, acc1, 0, 0, 0);
        acc2 = __builtin_amdgcn_mfma_f32_16x16x32_bf16(a, b2, acc2, 0, 0, 0);
        acc3 = __builtin_amdgcn_mfma_f32_16x16x32_bf16(a, b3, acc3, 0, 0, 0);
    }
#pragma unroll
    for (int r = 0; r < 4; ++r) {
        int gr = r0 + w * 16 + quad * 4 + r;
        if (gr < N) {
            float dn = dis[gr];
            size_t base = (size_t)gr * 64 + m;
            hs[base + 0]  = f2bf(acc0[r] * dn);
            hs[base + 16] = f2bf(acc1[r] * dn);
            hs[base + 32] = f2bf(acc2[r] * dn);
            hs[base + 48] = f2bf(acc3[r] * dn);
        }
    }
}

// One wave per node. lane = eslot(0..7) x ch-octet(0..7). 16B uint4 gathers
// -> 8 edges per VMEM instruction. Padded x16 lists (dummy src=N). bf16 out.
template <int RELU>
__global__ __launch_bounds__(256) void k_agg(const unsigned short* __restrict__ hs,
                                             const int* __restrict__ rowptr,
                                             const int* __restrict__ deg,
                                             const int* __restrict__ colidx,
                                             const float* __restrict__ dis,
                                             const float* __restrict__ bias,
                                             unsigned short* __restrict__ outp,
                                             int N) {
    int node = blockIdx.x * 4 + (threadIdx.x >> 6);
    if (node >= N) return;
    int lane = threadIdx.x & 63;
    int eslot = lane >> 3;   // 0..7
    int cq = lane & 7;       // channel octet

    int start = rowptr[node];
    int cnt = deg[node];
    int pcnt = (cnt + 15) & ~15;
    const int* ci = colidx + start + eslot;
    float acc[8] = {0.f, 0.f, 0.f, 0.f, 0.f, 0.f, 0.f, 0.f};

    int i = 0;
    if (pcnt & 16) {
        int s0 = ci[0], s1 = ci[8];
        uint4 a0 = *(const uint4*)&hs[(size_t)s0 * 64 + cq * 8];
        uint4 a1 = *(const uint4*)&hs[(size_t)s1 * 64 + cq * 8];
        acc8(acc, a0);
        acc8(acc, a1);
        i = 16;
    }
    for (; i < pcnt; i += 32) {
        int s0 = ci[i + 0], s1 = ci[i + 8], s2 = ci[i + 16], s3 = ci[i + 24];
        uint4 a0 = *(const uint4*)&hs[(size_t)s0 * 64 + cq * 8];
        uint4 a1 = *(const uint4*)&hs[(size_t)s1 * 64 + cq * 8];
        uint4 a2 = *(const uint4*)&hs[(size_t)s2 * 64 + cq * 8];
        uint4 a3 = *(const uint4*)&hs[(size_t)s3 * 64 + cq * 8];
        acc8(acc, a0);
        acc8(acc, a1);
        acc8(acc, a2);
        acc8(acc, a3);
    }

#pragma unroll
    for (int c = 0; c < 8; ++c) {
        acc[c] += __shfl_xor(acc[c], 8, 64);
        acc[c] += __shfl_xor(acc[c], 16, 64);
        acc[c] += __shfl_xor(acc[c], 32, 64);
    }

    if (eslot == 0) {
        uint4 sv = *(const uint4*)&hs[(size_t)node * 64 + cq * 8];
        float sf[8];
        unp8(sf, sv);
        float dn = dis[node];
        float4 blo = *(const float4*)&bias[cq * 8];
        float4 bhi = *(const float4*)&bias[cq * 8 + 4];
        float bb[8] = {blo.x, blo.y, blo.z, blo.w, bhi.x, bhi.y, bhi.z, bhi.w};
        unsigned short o[8];
#pragma unroll
        for (int c = 0; c < 8; ++c) {
            float v = dn * (acc[c] + sf[c]) + bb[c];
            if (RELU) v = fmaxf(v, 0.f);
            o[c] = f2bf(v);
        }
        uint4 ov;
        ov.x = (unsigned int)o[0] | ((unsigned int)o[1] << 16);
        ov.y = (unsigned int)o[2] | ((unsigned int)o[3] << 16);
        ov.z = (unsigned int)o[4] | ((unsigned int)o[5] << 16);
        ov.w = (unsigned int)o[6] | ((unsigned int)o[7] << 16);
        *(uint4*)&outp[(size_t)node * 64 + cq * 8] = ov;
    }
}

// Fused mean-pool + FC head: one wave per graph (binary-search node range in
// sorted batch, stream-sum bf16 rows, 64x10 matvec).
__global__ __launch_bounds__(64) void k_head2(const unsigned short* __restrict__ h,
                                              const int* __restrict__ batch,
                                              const float* __restrict__ Wfc,
                                              const float* __restrict__ bfc,
                                              float* __restrict__ out, int N) {
    __shared__ float p[64];
    int g = blockIdx.x, t = threadIdx.x;
    int lo = 0, hi = N;
    while (lo < hi) { int mid = (lo + hi) >> 1; if (batch[mid] < g) lo = mid + 1; else hi = mid; }
    int s = lo;
    hi = N;
    while (lo < hi) { int mid = (lo + hi) >> 1; if (batch[mid] < g + 1) lo = mid + 1; else hi = mid; }
    int e = lo;
    float acc = 0.f;
    int n = s;
    for (; n + 4 <= e; n += 4) {
        float a0 = bf2f(h[(size_t)(n + 0) * 64 + t]);
        float a1 = bf2f(h[(size_t)(n + 1) * 64 + t]);
        float a2 = bf2f(h[(size_t)(n + 2) * 64 + t]);
        float a3 = bf2f(h[(size_t)(n + 3) * 64 + t]);
        acc += (a0 + a1) + (a2 + a3);
    }
    for (; n < e; ++n) acc += bf2f(h[(size_t)n * 64 + t]);
    float cnt = (float)max(e - s, 1);
    p[t] = acc / cnt;
    __syncthreads();
    if (t < 10) {
        float o = bfc[t];
#pragma unroll
        for (int hh = 0; hh < 64; ++hh) o += p[hh] * Wfc[hh * 10 + t];
        out[g * 10 + t] = o;
    }
}

extern "C" void kernel_launch(void* const* d_in, const int* in_sizes, int n_in,
                              void* d_out, int out_size, void* d_ws, size_t ws_size,
                              hipStream_t stream) {
    const float* x = (const float*)d_in[0];
    const int* eidx = (const int*)d_in[1];
    const int* batch = (const int*)d_in[2];
    const float* W1 = (const float*)d_in[3];
    const float* b1 = (const float*)d_in[4];
    const float* W2 = (const float*)d_in[5];
    const float* b2 = (const float*)d_in[6];
    const float* W3 = (const float*)d_in[7];
    const float* b3 = (const float*)d_in[8];
    const float* Wfc = (const float*)d_in[9];
    const float* bfc = (const float*)d_in[10];
    float* out = (float*)d_out;

    const int N = in_sizes[0] / 128;  // 100000
    const int E = in_sizes[1] / 2;    // 3200000
    const int G = out_size / 10;      // 512
    const int NB = (N + 255) / 256;   // 391 buckets
    int chunk = ((E + NBLK - 1) / NBLK + 3) & ~3;  // 16B-aligned chunk starts

    char* ws = (char*)d_ws;
    size_t off = 0;
    auto alloc = [&](size_t bytes) -> char* {
        char* p = ws + off;
        off = (off + bytes + 511) & ~(size_t)511;
        return p;
    };
    int* deg = (int*)alloc((size_t)N * 4);
    int* rowptr = (int*)alloc((size_t)N * 4);
    float* dis = (float*)alloc((size_t)N * 4);
    int* starts = (int*)alloc((size_t)(MAXNB + 1) * 4);
    int* btotal = (int*)alloc((size_t)MAXNB * 4);
    int* blockhist = (int*)alloc((size_t)NB * NBLK * 4);
    unsigned int* epart = (unsigned int*)alloc((size_t)E * 4);
    int* colidx = (int*)alloc(((size_t)E + (size_t)NB * BPAD) * 4);
    unsigned short* hsA = (unsigned short*)alloc((size_t)(N + 1) * 64 * 2);
    unsigned short* hsB = (unsigned short*)alloc((size_t)(N + 1) * 64 * 2);
    unsigned short* obufb = (unsigned short*)alloc((size_t)N * 64 * 2);

    const int* esrc = eidx;
    const int* edst = eidx + E;

    k_hist<<<NBLK, 256, 0, stream>>>(edst, blockhist, E, chunk, NB);
    k_bscan<<<NB, 256, 0, stream>>>(blockhist, btotal);
    k_sscan<<<1, 256, 0, stream>>>(btotal, starts, NB, hsA, hsB, N);
    k_part<<<NBLK, 256, 0, stream>>>(esrc, edst, blockhist, starts, epart, E, chunk, NB);
    k_fine<<<NB, 256, 0, stream>>>(epart, starts, deg, rowptr, dis, colidx, N);

    int gblk = (N + 63) / 64;
    k_gemm_mfma<128, 0><<<gblk, 256, 0, stream>>>(x, W1, dis, hsA, N);
    k_agg<1><<<(N + 3) / 4, 256, 0, stream>>>(hsA, rowptr, deg, colidx, dis, b1, obufb, N);
    k_gemm_mfma<64, 1><<<gblk, 256, 0, stream>>>(obufb, W2, dis, hsB, N);
    k_agg<1><<<(N + 3) / 4, 256, 0, stream>>>(hsB, rowptr, deg, colidx, dis, b2, obufb, N);
    k_gemm_mfma<64, 1><<<gblk, 256, 0, stream>>>(obufb, W3, dis, hsA, N);
    k_agg<0><<<(N + 3) / 4, 256, 0, stream>>>(hsA, rowptr, deg, colidx, dis, b3, obufb, N);

    k_head2<<<G, 64, 0, stream>>>(obufb, batch, Wfc, bfc, out, N);
}